// Round 19
// baseline (81.869 us; speedup 1.0000x reference)
//
#include <hip/hip_runtime.h>
#include <hip/hip_bf16.h>

// GCN layer: out = A_hat @ (x @ W) + bias,  A_hat = D^-1/2 (A+I) D^-1/2.
// N=50000, E=600000, IN=128, OUT=64.
//
// GEMM history: r13 W-LDS+x-broadcast 45us (grid=4/CU + VGPR=52 killed ILP);
// r15/r16 manual prefetch = scratch spill; r17 no-LDS = 71us (192 vmem
// instrs/thread); r18 X+W-LDS 64KB = 60us (2 blocks/CU, occupancy 13%).
// r19: W-LDS (32KB) + NPB=32 (thread = 2 nodes x 4ch) + 1813-block grid ->
// LDS-capped 5 blocks/CU, ~20 waves/CU; 72 vmem instrs/thread; 8 accum
// VGPRs leave headroom for the compiler to buffer x-loads (unroll 16).
//
// Pipeline (3 kernels):
//   1) zero_cnt
//   2) MEGA role-split: [0,1563) gemm tiles; [1563,1813) bucket grid-stride.
//   3) gather (r10 best): wave/node, tiered 8/4 loads in flight, block=128.
//
// NOTE: "fillBufferAligned 256MB" profile rows = HARNESS d_ws poisoning.
// NOTE: coop launch fails silently (r9); NT hints +13us (r8); VGPR caps or
// hand-unrolled rings => scratch spill (r3/r15/r16).
//
// ws: [cnt: N int][y: N*64 ushort(bf16)][bucket: N*64 int]

#define IN_CH 128
#define OUT_CH 64
#define CAP 64
#define NPB 32                 // nodes per gemm block (thread = 2 nodes x 4 ch)
#define GEMM_BLOCKS 1563       // ceil(50000/32)
#define BUCKET_BLOCKS 250
#define TOTAL_BLOCKS (GEMM_BLOCKS + BUCKET_BLOCKS)

__global__ void zero_cnt_kernel(int* __restrict__ cnt, int n) {
    int i = blockIdx.x * blockDim.x + threadIdx.x;
    if (i < n) cnt[i] = 0;
}

__device__ __forceinline__ unsigned short f2bf(float f) {
    unsigned int u = __float_as_uint(f);
    unsigned int r = (u + 0x7fffu + ((u >> 16) & 1u)) >> 16;  // RTN-even
    return (unsigned short)r;
}

#define FMA4(A, xs, Wv) \
    A.x = fmaf(xs, Wv.x, A.x); A.y = fmaf(xs, Wv.y, A.y); \
    A.z = fmaf(xs, Wv.z, A.z); A.w = fmaf(xs, Wv.w, A.w);

__global__ __launch_bounds__(256) void mega_kernel(const float* __restrict__ x,
                                                   const float* __restrict__ w,
                                                   const int* __restrict__ ei,
                                                   unsigned short* __restrict__ y,
                                                   int* __restrict__ cnt,
                                                   int* __restrict__ bucket,
                                                   int n, int nE) {
    __shared__ float wl[IN_CH * OUT_CH];   // 32 KB (gemm role only)
    const int t = threadIdx.x;

    if (blockIdx.x >= GEMM_BLOCKS) {
        // ---- bucket role: grid-stride over edge pairs ----
        const int nPairs = (nE + 1) / 2;
        const int stride = BUCKET_BLOCKS * 256;
        for (int p = (blockIdx.x - GEMM_BLOCKS) * 256 + t; p < nPairs; p += stride) {
            int e0 = p * 2;
            int2 s2 = reinterpret_cast<const int2*>(ei)[p];
            int2 d2 = reinterpret_cast<const int2*>(ei + nE)[p];
            int pos0 = atomicAdd(&cnt[d2.x], 1);
            if (pos0 < CAP) bucket[(size_t)d2.x * CAP + pos0] = s2.x;
            if (e0 + 1 < nE) {
                int pos1 = atomicAdd(&cnt[d2.y], 1);
                if (pos1 < CAP) bucket[(size_t)d2.y * CAP + pos1] = s2.y;
            }
        }
        return;
    }

    // ---- gemm role: 32 nodes/block, thread = 2 nodes x 4 channels ----
    const int base = blockIdx.x * NPB;
    {   // stage W (coalesced float4; L2-hot after first wave of blocks)
        const float4* w4 = reinterpret_cast<const float4*>(w);
        float4* wl4 = reinterpret_cast<float4*>(wl);
        #pragma unroll
        for (int i = 0; i < 8; ++i) wl4[t + i * 256] = w4[t + i * 256];
    }
    __syncthreads();

    const int nq = t >> 4;          // 0..15
    const int cq = t & 15;          // 0..15
    const int n0 = base + nq * 2;   // this thread's 2 node rows
    const int c0 = cq * 4;

    const float4* xr0 = reinterpret_cast<const float4*>(x + (size_t)min(n0 + 0, n - 1) * IN_CH);
    const float4* xr1 = reinterpret_cast<const float4*>(x + (size_t)min(n0 + 1, n - 1) * IN_CH);
    const float4* wl4 = reinterpret_cast<const float4*>(wl);

    float4 A0 = make_float4(0.f, 0.f, 0.f, 0.f);
    float4 A1 = A0;

    #pragma unroll 16
    for (int k4 = 0; k4 < IN_CH / 4; ++k4) {
        const float4 X0 = xr0[k4];                 // same-addr broadcast across 16 cq lanes
        const float4 X1 = xr1[k4];
        const float4 W0 = wl4[(k4 * 4 + 0) * 16 + cq];
        const float4 W1 = wl4[(k4 * 4 + 1) * 16 + cq];
        const float4 W2 = wl4[(k4 * 4 + 2) * 16 + cq];
        const float4 W3 = wl4[(k4 * 4 + 3) * 16 + cq];
        FMA4(A0, X0.x, W0) FMA4(A0, X0.y, W1) FMA4(A0, X0.z, W2) FMA4(A0, X0.w, W3)
        FMA4(A1, X1.x, W0) FMA4(A1, X1.y, W1) FMA4(A1, X1.z, W2) FMA4(A1, X1.w, W3)
    }

    #define STORE_ROW(J, A)                                                            \
        if (n0 + J < n) {                                                              \
            uint2 pk;                                                                  \
            pk.x = (unsigned int)f2bf(A.x) | ((unsigned int)f2bf(A.y) << 16);          \
            pk.y = (unsigned int)f2bf(A.z) | ((unsigned int)f2bf(A.w) << 16);          \
            *reinterpret_cast<uint2*>(&y[(size_t)(n0 + J) * OUT_CH + c0]) = pk;        \
        }
    STORE_ROW(0, A0)
    STORE_ROW(1, A1)
    #undef STORE_ROW
}

// Gather (round-10 best): one wave per node, block=128 (32 waves/CU).
#define EDGE_FMA(c, v) \
    ax = fmaf(c, __uint_as_float((v) << 16), ax); \
    ay = fmaf(c, __uint_as_float((v) & 0xffff0000u), ay);

__global__ __launch_bounds__(128) void gather_kernel(const int* __restrict__ cnt,
                                                     const int* __restrict__ bucket,
                                                     const unsigned short* __restrict__ y,
                                                     const float* __restrict__ bias,
                                                     float* __restrict__ out, int n) {
    const int wid  = threadIdx.x >> 6;
    const int lane = threadIdx.x & 63;
    const int nid  = blockIdx.x * 2 + wid;
    if (nid >= n) return;
    const int hw = lane >> 5;
    const int cp = lane & 31;

    int deg = cnt[nid];
    if (deg > CAP) deg = CAP;
    const float isd_d = rsqrtf((float)cnt[nid] + 1.0f);

    int   s_l  = 0;
    float cf_l = 0.f;
    if (lane < deg) {
        s_l  = bucket[(size_t)nid * CAP + lane];
        cf_l = isd_d * rsqrtf((float)cnt[s_l] + 1.0f);
    }

    float ax = 0.f, ay = 0.f;
    if (hw == 0) {
        float2 b2 = reinterpret_cast<const float2*>(bias)[cp];
        unsigned int u = reinterpret_cast<const unsigned int*>(y + (size_t)nid * OUT_CH)[cp];
        float sl = isd_d * isd_d;
        ax = fmaf(sl, __uint_as_float(u << 16), b2.x);
        ay = fmaf(sl, __uint_as_float(u & 0xffff0000u), b2.y);
    }

    for (int k = 0; k < deg; k += 16) {
        int rem = deg - k;
        if (rem > 8) {
            int s0 = __shfl(s_l, k + 0 + hw),  s1 = __shfl(s_l, k + 2 + hw);
            int s2 = __shfl(s_l, k + 4 + hw),  s3 = __shfl(s_l, k + 6 + hw);
            int s4 = __shfl(s_l, k + 8 + hw),  s5 = __shfl(s_l, k + 10 + hw);
            int s6 = __shfl(s_l, k + 12 + hw), s7 = __shfl(s_l, k + 14 + hw);
            unsigned int v0 = reinterpret_cast<const unsigned int*>(y + (size_t)s0 * OUT_CH)[cp];
            unsigned int v1 = reinterpret_cast<const unsigned int*>(y + (size_t)s1 * OUT_CH)[cp];
            unsigned int v2 = reinterpret_cast<const unsigned int*>(y + (size_t)s2 * OUT_CH)[cp];
            unsigned int v3 = reinterpret_cast<const unsigned int*>(y + (size_t)s3 * OUT_CH)[cp];
            unsigned int v4 = reinterpret_cast<const unsigned int*>(y + (size_t)s4 * OUT_CH)[cp];
            unsigned int v5 = reinterpret_cast<const unsigned int*>(y + (size_t)s5 * OUT_CH)[cp];
            unsigned int v6 = reinterpret_cast<const unsigned int*>(y + (size_t)s6 * OUT_CH)[cp];
            unsigned int v7 = reinterpret_cast<const unsigned int*>(y + (size_t)s7 * OUT_CH)[cp];
            float c0 = __shfl(cf_l, k + 0 + hw),  c1 = __shfl(cf_l, k + 2 + hw);
            float c2 = __shfl(cf_l, k + 4 + hw),  c3 = __shfl(cf_l, k + 6 + hw);
            float c4 = __shfl(cf_l, k + 8 + hw),  c5 = __shfl(cf_l, k + 10 + hw);
            float c6 = __shfl(cf_l, k + 12 + hw), c7 = __shfl(cf_l, k + 14 + hw);
            EDGE_FMA(c0, v0) EDGE_FMA(c1, v1) EDGE_FMA(c2, v2) EDGE_FMA(c3, v3)
            EDGE_FMA(c4, v4) EDGE_FMA(c5, v5) EDGE_FMA(c6, v6) EDGE_FMA(c7, v7)
        } else {
            int s0 = __shfl(s_l, k + 0 + hw), s1 = __shfl(s_l, k + 2 + hw);
            int s2 = __shfl(s_l, k + 4 + hw), s3 = __shfl(s_l, k + 6 + hw);
            unsigned int v0 = reinterpret_cast<const unsigned int*>(y + (size_t)s0 * OUT_CH)[cp];
            unsigned int v1 = reinterpret_cast<const unsigned int*>(y + (size_t)s1 * OUT_CH)[cp];
            unsigned int v2 = reinterpret_cast<const unsigned int*>(y + (size_t)s2 * OUT_CH)[cp];
            unsigned int v3 = reinterpret_cast<const unsigned int*>(y + (size_t)s3 * OUT_CH)[cp];
            float c0 = __shfl(cf_l, k + 0 + hw), c1 = __shfl(cf_l, k + 2 + hw);
            float c2 = __shfl(cf_l, k + 4 + hw), c3 = __shfl(cf_l, k + 6 + hw);
            EDGE_FMA(c0, v0) EDGE_FMA(c1, v1) EDGE_FMA(c2, v2) EDGE_FMA(c3, v3)
        }
    }

    ax += __shfl_xor(ax, 32);
    ay += __shfl_xor(ay, 32);
    if (hw == 0) {
        float2 o; o.x = ax; o.y = ay;
        reinterpret_cast<float2*>(out + (size_t)nid * OUT_CH)[cp] = o;
    }
}

extern "C" void kernel_launch(void* const* d_in, const int* in_sizes, int n_in,
                              void* d_out, int out_size, void* d_ws, size_t ws_size,
                              hipStream_t stream) {
    const float* x    = (const float*)d_in[0];
    const int*   ei   = (const int*)d_in[1];
    const float* w    = (const float*)d_in[2];
    const float* bias = (const float*)d_in[3];
    float* out = (float*)d_out;

    const int n  = in_sizes[0] / IN_CH;   // 50000
    const int nE = in_sizes[1] / 2;       // 600000

    char* p = (char*)d_ws;
    auto align256 = [](size_t v) { return (v + 255) & ~(size_t)255; };
    int*            cnt    = (int*)p;             p += align256((size_t)n * 4);
    unsigned short* y      = (unsigned short*)p;  p += align256((size_t)n * OUT_CH * 2);
    int*            bucket = (int*)p;

    zero_cnt_kernel<<<(n + 255) / 256, 256, 0, stream>>>(cnt, n);
    mega_kernel<<<TOTAL_BLOCKS, 256, 0, stream>>>(x, w, ei, y, cnt, bucket, n, nE);
    gather_kernel<<<(n + 1) / 2, 128, 0, stream>>>(cnt, bucket, y, bias, out, n);
}

// Round 20
// 77.474 us; speedup vs baseline: 1.0567x; 1.0567x over previous
//
#include <hip/hip_runtime.h>
#include <hip/hip_bf16.h>

// GCN layer: out = A_hat @ (x @ W) + bias,  A_hat = D^-1/2 (A+I) D^-1/2.
// N=50000, E=600000, IN=128, OUT=64.
//
// GEMM history: f32 VALU versions stuck at 45-71us across 4 structures
// (r13/r17/r18/r19) - latency/LDS/issue tradeoffs can't all be met.
// r20: bf16 MFMA (mfma_f32_16x16x32_bf16), NO LDS, NO barrier:
//   - A-frag: lane reads x[rbase+(l&15)][s*32+(l>>4)*8 ..+8) as 2 float4,
//     cvt to bf16x8 (RNE). Lanes sharing a 128B line merge -> x read once.
//   - B-frag: wt[n][k] bf16 (W^T, built once in zero_prep) is 16KB ->
//     L1-resident; lane reads 16B at wt[16*tl+(l&15)][s*32+(l>>4)*8].
//   - C/D: col=lane&15, row=(lane>>4)*4+reg (m89-verified layout).
//   Per thread: 8 x-loads + 16 wt-loads + 16 mfma + 16 stores.
//
// Pipeline (3 kernels):
//   1) zero_prep: cnt=0; block 0 also builds wt = bf16(W^T)
//   2) MEGA role-split: [0,782) mfma-gemm tiles; [782,1024) bucket fill.
//   3) gather (r10 best): wave/node, tiered 8/4 loads in flight, block=128.
//
// NOTE: "fillBufferAligned 256MB" profile rows = HARNESS d_ws poisoning.
// NOTE: coop launch fails silently (r9); NT hints +13us (r8); VGPR caps or
// hand-unrolled f32 prefetch rings => scratch spill (r3/r15/r16).
//
// ws: [cnt: N int][y: N*64 ushort(bf16)][bucket: N*64 int][wt: 8192 ushort]

#define IN_CH 128
#define OUT_CH 64
#define CAP 64
#define NPB 64
#define GEMM_BLOCKS 782   // ceil(50000/64)
#define BUCKET_BLOCKS 242
#define TOTAL_BLOCKS (GEMM_BLOCKS + BUCKET_BLOCKS)

typedef short short8 __attribute__((ext_vector_type(8)));   // 8 bf16 (4 VGPRs)
typedef float f32x4  __attribute__((ext_vector_type(4)));   // MFMA accum

__device__ __forceinline__ unsigned short f2bf(float f) {
    unsigned int u = __float_as_uint(f);
    unsigned int r = (u + 0x7fffu + ((u >> 16) & 1u)) >> 16;  // RTN-even
    return (unsigned short)r;
}

__device__ __forceinline__ short8 cvt_bf16x8(float4 a, float4 b) {
    short8 r;
    r[0] = (short)f2bf(a.x); r[1] = (short)f2bf(a.y);
    r[2] = (short)f2bf(a.z); r[3] = (short)f2bf(a.w);
    r[4] = (short)f2bf(b.x); r[5] = (short)f2bf(b.y);
    r[6] = (short)f2bf(b.z); r[7] = (short)f2bf(b.w);
    return r;
}

// zero cnt; block 0 additionally builds wt[n][k] = bf16(w[k][n])
__global__ void zero_prep_kernel(int* __restrict__ cnt, const float* __restrict__ w,
                                 unsigned short* __restrict__ wt, int n) {
    int i = blockIdx.x * 256 + threadIdx.x;
    if (i < n) cnt[i] = 0;
    if (blockIdx.x == 0) {
        for (int j = threadIdx.x; j < IN_CH * OUT_CH; j += 256) {
            int k = j >> 6, nn = j & 63;       // w[k][n] row-major
            wt[nn * IN_CH + k] = f2bf(w[j]);
        }
    }
}

__global__ __launch_bounds__(256) void mega_kernel(const float* __restrict__ x,
                                                   const unsigned short* __restrict__ wt,
                                                   const int* __restrict__ ei,
                                                   unsigned short* __restrict__ y,
                                                   int* __restrict__ cnt,
                                                   int* __restrict__ bucket,
                                                   int n, int nE) {
    const int t = threadIdx.x;

    if (blockIdx.x >= GEMM_BLOCKS) {
        // ---- bucket role: grid-stride over edge pairs ----
        const int nPairs = (nE + 1) / 2;
        const int stride = BUCKET_BLOCKS * 256;
        for (int p = (blockIdx.x - GEMM_BLOCKS) * 256 + t; p < nPairs; p += stride) {
            int e0 = p * 2;
            int2 s2 = reinterpret_cast<const int2*>(ei)[p];
            int2 d2 = reinterpret_cast<const int2*>(ei + nE)[p];
            int pos0 = atomicAdd(&cnt[d2.x], 1);
            if (pos0 < CAP) bucket[(size_t)d2.x * CAP + pos0] = s2.x;
            if (e0 + 1 < nE) {
                int pos1 = atomicAdd(&cnt[d2.y], 1);
                if (pos1 < CAP) bucket[(size_t)d2.y * CAP + pos1] = s2.y;
            }
        }
        return;
    }

    // ---- gemm role: 4 waves/block, each wave = 16 rows x 64 cols ----
    const int wv    = t >> 6;
    const int l     = t & 63;
    const int cl    = l & 15;       // A-row / B-col / C-col within tile
    const int koct  = l >> 4;       // k-octet 0..3
    const int rbase = blockIdx.x * NPB + wv * 16;

    const int gr = min(rbase + cl, n - 1);   // A-row (clamped; stores guarded)
    const float4* xr = reinterpret_cast<const float4*>(x + (size_t)gr * IN_CH);

    f32x4 c0 = {0.f, 0.f, 0.f, 0.f};
    f32x4 c1 = c0, c2 = c0, c3 = c0;

    #define KSTEP(S) { \
        const float4 u = xr[(S) * 8 + koct * 2]; \
        const float4 v = xr[(S) * 8 + koct * 2 + 1]; \
        const short8 a8 = cvt_bf16x8(u, v); \
        const short8 b0 = *reinterpret_cast<const short8*>(wt + ( 0 + cl) * IN_CH + (S) * 32 + koct * 8); \
        const short8 b1 = *reinterpret_cast<const short8*>(wt + (16 + cl) * IN_CH + (S) * 32 + koct * 8); \
        const short8 b2 = *reinterpret_cast<const short8*>(wt + (32 + cl) * IN_CH + (S) * 32 + koct * 8); \
        const short8 b3 = *reinterpret_cast<const short8*>(wt + (48 + cl) * IN_CH + (S) * 32 + koct * 8); \
        c0 = __builtin_amdgcn_mfma_f32_16x16x32_bf16(a8, b0, c0, 0, 0, 0); \
        c1 = __builtin_amdgcn_mfma_f32_16x16x32_bf16(a8, b1, c1, 0, 0, 0); \
        c2 = __builtin_amdgcn_mfma_f32_16x16x32_bf16(a8, b2, c2, 0, 0, 0); \
        c3 = __builtin_amdgcn_mfma_f32_16x16x32_bf16(a8, b3, c3, 0, 0, 0); }
    KSTEP(0) KSTEP(1) KSTEP(2) KSTEP(3)
    #undef KSTEP

    // C/D layout: col = lane&15, row = (lane>>4)*4 + reg  [m89-verified]
    #pragma unroll
    for (int r = 0; r < 4; ++r) {
        int grow = rbase + koct * 4 + r;
        if (grow < n) {
            unsigned short* yp = y + (size_t)grow * OUT_CH + cl;
            yp[0]  = f2bf(c0[r]);
            yp[16] = f2bf(c1[r]);
            yp[32] = f2bf(c2[r]);
            yp[48] = f2bf(c3[r]);
        }
    }
}

// Gather (round-10 best): one wave per node, block=128 (32 waves/CU).
#define EDGE_FMA(c, v) \
    ax = fmaf(c, __uint_as_float((v) << 16), ax); \
    ay = fmaf(c, __uint_as_float((v) & 0xffff0000u), ay);

__global__ __launch_bounds__(128) void gather_kernel(const int* __restrict__ cnt,
                                                     const int* __restrict__ bucket,
                                                     const unsigned short* __restrict__ y,
                                                     const float* __restrict__ bias,
                                                     float* __restrict__ out, int n) {
    const int wid  = threadIdx.x >> 6;
    const int lane = threadIdx.x & 63;
    const int nid  = blockIdx.x * 2 + wid;
    if (nid >= n) return;
    const int hw = lane >> 5;
    const int cp = lane & 31;

    int deg = cnt[nid];
    if (deg > CAP) deg = CAP;
    const float isd_d = rsqrtf((float)cnt[nid] + 1.0f);

    int   s_l  = 0;
    float cf_l = 0.f;
    if (lane < deg) {
        s_l  = bucket[(size_t)nid * CAP + lane];
        cf_l = isd_d * rsqrtf((float)cnt[s_l] + 1.0f);
    }

    float ax = 0.f, ay = 0.f;
    if (hw == 0) {
        float2 b2 = reinterpret_cast<const float2*>(bias)[cp];
        unsigned int u = reinterpret_cast<const unsigned int*>(y + (size_t)nid * OUT_CH)[cp];
        float sl = isd_d * isd_d;
        ax = fmaf(sl, __uint_as_float(u << 16), b2.x);
        ay = fmaf(sl, __uint_as_float(u & 0xffff0000u), b2.y);
    }

    for (int k = 0; k < deg; k += 16) {
        int rem = deg - k;
        if (rem > 8) {
            int s0 = __shfl(s_l, k + 0 + hw),  s1 = __shfl(s_l, k + 2 + hw);
            int s2 = __shfl(s_l, k + 4 + hw),  s3 = __shfl(s_l, k + 6 + hw);
            int s4 = __shfl(s_l, k + 8 + hw),  s5 = __shfl(s_l, k + 10 + hw);
            int s6 = __shfl(s_l, k + 12 + hw), s7 = __shfl(s_l, k + 14 + hw);
            unsigned int v0 = reinterpret_cast<const unsigned int*>(y + (size_t)s0 * OUT_CH)[cp];
            unsigned int v1 = reinterpret_cast<const unsigned int*>(y + (size_t)s1 * OUT_CH)[cp];
            unsigned int v2 = reinterpret_cast<const unsigned int*>(y + (size_t)s2 * OUT_CH)[cp];
            unsigned int v3 = reinterpret_cast<const unsigned int*>(y + (size_t)s3 * OUT_CH)[cp];
            unsigned int v4 = reinterpret_cast<const unsigned int*>(y + (size_t)s4 * OUT_CH)[cp];
            unsigned int v5 = reinterpret_cast<const unsigned int*>(y + (size_t)s5 * OUT_CH)[cp];
            unsigned int v6 = reinterpret_cast<const unsigned int*>(y + (size_t)s6 * OUT_CH)[cp];
            unsigned int v7 = reinterpret_cast<const unsigned int*>(y + (size_t)s7 * OUT_CH)[cp];
            float c0 = __shfl(cf_l, k + 0 + hw),  c1 = __shfl(cf_l, k + 2 + hw);
            float c2 = __shfl(cf_l, k + 4 + hw),  c3 = __shfl(cf_l, k + 6 + hw);
            float c4 = __shfl(cf_l, k + 8 + hw),  c5 = __shfl(cf_l, k + 10 + hw);
            float c6 = __shfl(cf_l, k + 12 + hw), c7 = __shfl(cf_l, k + 14 + hw);
            EDGE_FMA(c0, v0) EDGE_FMA(c1, v1) EDGE_FMA(c2, v2) EDGE_FMA(c3, v3)
            EDGE_FMA(c4, v4) EDGE_FMA(c5, v5) EDGE_FMA(c6, v6) EDGE_FMA(c7, v7)
        } else {
            int s0 = __shfl(s_l, k + 0 + hw), s1 = __shfl(s_l, k + 2 + hw);
            int s2 = __shfl(s_l, k + 4 + hw), s3 = __shfl(s_l, k + 6 + hw);
            unsigned int v0 = reinterpret_cast<const unsigned int*>(y + (size_t)s0 * OUT_CH)[cp];
            unsigned int v1 = reinterpret_cast<const unsigned int*>(y + (size_t)s1 * OUT_CH)[cp];
            unsigned int v2 = reinterpret_cast<const unsigned int*>(y + (size_t)s2 * OUT_CH)[cp];
            unsigned int v3 = reinterpret_cast<const unsigned int*>(y + (size_t)s3 * OUT_CH)[cp];
            float c0 = __shfl(cf_l, k + 0 + hw), c1 = __shfl(cf_l, k + 2 + hw);
            float c2 = __shfl(cf_l, k + 4 + hw), c3 = __shfl(cf_l, k + 6 + hw);
            EDGE_FMA(c0, v0) EDGE_FMA(c1, v1) EDGE_FMA(c2, v2) EDGE_FMA(c3, v3)
        }
    }

    ax += __shfl_xor(ax, 32);
    ay += __shfl_xor(ay, 32);
    if (hw == 0) {
        float2 o; o.x = ax; o.y = ay;
        reinterpret_cast<float2*>(out + (size_t)nid * OUT_CH)[cp] = o;
    }
}

extern "C" void kernel_launch(void* const* d_in, const int* in_sizes, int n_in,
                              void* d_out, int out_size, void* d_ws, size_t ws_size,
                              hipStream_t stream) {
    const float* x    = (const float*)d_in[0];
    const int*   ei   = (const int*)d_in[1];
    const float* w    = (const float*)d_in[2];
    const float* bias = (const float*)d_in[3];
    float* out = (float*)d_out;

    const int n  = in_sizes[0] / IN_CH;   // 50000
    const int nE = in_sizes[1] / 2;       // 600000

    char* p = (char*)d_ws;
    auto align256 = [](size_t v) { return (v + 255) & ~(size_t)255; };
    int*            cnt    = (int*)p;             p += align256((size_t)n * 4);
    unsigned short* y      = (unsigned short*)p;  p += align256((size_t)n * OUT_CH * 2);
    int*            bucket = (int*)p;             p += align256((size_t)n * CAP * 4);
    unsigned short* wt     = (unsigned short*)p;  // 8192 ushort

    // 1) cnt = 0 and wt = bf16(W^T)
    zero_prep_kernel<<<(n + 255) / 256, 256, 0, stream>>>(cnt, w, wt, n);
    // 2) mfma-gemm blocks || bucket blocks
    mega_kernel<<<TOTAL_BLOCKS, 256, 0, stream>>>(x, wt, ei, y, cnt, bucket, n, nE);
    // 3) gather
    gather_kernel<<<(n + 1) / 2, 128, 0, stream>>>(cnt, bucket, y, bias, out, n);
}

// Round 21
// 74.058 us; speedup vs baseline: 1.1055x; 1.0461x over previous
//
#include <hip/hip_runtime.h>
#include <hip/hip_bf16.h>

// GCN layer: out = A_hat @ (x @ W) + bias,  A_hat = D^-1/2 (A+I) D^-1/2.
// N=50000, E=600000, IN=128, OUT=64.
//
// r20 found: gemm-as-MFMA is cheap (MfmaUtil>0, VALU 1.8%) but mega stayed
// 55us -> the 242-block grid-stride BUCKET role was the hidden long pole
// (4 waves/CU, ~5 serial atomic->store chains per thread, no TLP).
// r21: bucket gets 1172 blocks, ONE edge pair per thread, no loop (the
// proven-fast shape from rounds 2-12). gemm unchanged (r20 MFMA).
//
// Pipeline (3 kernels):
//   1) zero_prep: cnt=0; block 0 builds wt = bf16(W^T) (16KB, L1-resident)
//   2) MEGA: blocks [0,1172) bucket (1 pair/thread); [1172,1954) mfma-gemm.
//   3) gather (r10 best): wave/node, tiered 8/4 loads in flight, block=128.
//
// NOTE: "fillBufferAligned 256MB" profile rows = HARNESS d_ws poisoning.
// NOTE: coop launch fails silently (r9); NT hints +13us (r8); VGPR caps or
// hand-unrolled f32 prefetch rings => scratch spill (r3/r15/r16).
//
// ws: [cnt: N int][y: N*64 ushort(bf16)][bucket: N*64 int][wt: 8192 ushort]

#define IN_CH 128
#define OUT_CH 64
#define CAP 64
#define NPB 64
#define BUCKET_BLOCKS 1172   // ceil(300000 pairs / 256)
#define GEMM_BLOCKS 782      // ceil(50000/64)
#define TOTAL_BLOCKS (BUCKET_BLOCKS + GEMM_BLOCKS)

typedef short short8 __attribute__((ext_vector_type(8)));   // 8 bf16 (4 VGPRs)
typedef float f32x4  __attribute__((ext_vector_type(4)));   // MFMA accum

__device__ __forceinline__ unsigned short f2bf(float f) {
    unsigned int u = __float_as_uint(f);
    unsigned int r = (u + 0x7fffu + ((u >> 16) & 1u)) >> 16;  // RTN-even
    return (unsigned short)r;
}

__device__ __forceinline__ short8 cvt_bf16x8(float4 a, float4 b) {
    short8 r;
    r[0] = (short)f2bf(a.x); r[1] = (short)f2bf(a.y);
    r[2] = (short)f2bf(a.z); r[3] = (short)f2bf(a.w);
    r[4] = (short)f2bf(b.x); r[5] = (short)f2bf(b.y);
    r[6] = (short)f2bf(b.z); r[7] = (short)f2bf(b.w);
    return r;
}

// zero cnt; block 0 additionally builds wt[n][k] = bf16(w[k][n])
__global__ void zero_prep_kernel(int* __restrict__ cnt, const float* __restrict__ w,
                                 unsigned short* __restrict__ wt, int n) {
    int i = blockIdx.x * 256 + threadIdx.x;
    if (i < n) cnt[i] = 0;
    if (blockIdx.x == 0) {
        for (int j = threadIdx.x; j < IN_CH * OUT_CH; j += 256) {
            int k = j >> 6, nn = j & 63;       // w[k][n] row-major
            wt[nn * IN_CH + k] = f2bf(w[j]);
        }
    }
}

__global__ __launch_bounds__(256) void mega_kernel(const float* __restrict__ x,
                                                   const unsigned short* __restrict__ wt,
                                                   const int* __restrict__ ei,
                                                   unsigned short* __restrict__ y,
                                                   int* __restrict__ cnt,
                                                   int* __restrict__ bucket,
                                                   int n, int nE) {
    const int t = threadIdx.x;

    if (blockIdx.x < BUCKET_BLOCKS) {
        // ---- bucket role: ONE edge pair per thread (full TLP) ----
        const int nPairs = (nE + 1) / 2;
        int p = blockIdx.x * 256 + t;
        if (p < nPairs) {
            int e0 = p * 2;
            int2 s2 = reinterpret_cast<const int2*>(ei)[p];
            int2 d2 = reinterpret_cast<const int2*>(ei + nE)[p];
            int pos0 = atomicAdd(&cnt[d2.x], 1);
            if (pos0 < CAP) bucket[(size_t)d2.x * CAP + pos0] = s2.x;
            if (e0 + 1 < nE) {
                int pos1 = atomicAdd(&cnt[d2.y], 1);
                if (pos1 < CAP) bucket[(size_t)d2.y * CAP + pos1] = s2.y;
            }
        }
        return;
    }

    // ---- gemm role: 4 waves/block, each wave = 16 rows x 64 cols ----
    const int wv    = t >> 6;
    const int l     = t & 63;
    const int cl    = l & 15;       // A-row / B-col / C-col within tile
    const int koct  = l >> 4;       // k-octet 0..3
    const int rbase = (blockIdx.x - BUCKET_BLOCKS) * NPB + wv * 16;

    const int gr = min(rbase + cl, n - 1);   // A-row (clamped; stores guarded)
    const float4* xr = reinterpret_cast<const float4*>(x + (size_t)gr * IN_CH);

    f32x4 c0 = {0.f, 0.f, 0.f, 0.f};
    f32x4 c1 = c0, c2 = c0, c3 = c0;

    #define KSTEP(S) { \
        const float4 u = xr[(S) * 8 + koct * 2]; \
        const float4 v = xr[(S) * 8 + koct * 2 + 1]; \
        const short8 a8 = cvt_bf16x8(u, v); \
        const short8 b0 = *reinterpret_cast<const short8*>(wt + ( 0 + cl) * IN_CH + (S) * 32 + koct * 8); \
        const short8 b1 = *reinterpret_cast<const short8*>(wt + (16 + cl) * IN_CH + (S) * 32 + koct * 8); \
        const short8 b2 = *reinterpret_cast<const short8*>(wt + (32 + cl) * IN_CH + (S) * 32 + koct * 8); \
        const short8 b3 = *reinterpret_cast<const short8*>(wt + (48 + cl) * IN_CH + (S) * 32 + koct * 8); \
        c0 = __builtin_amdgcn_mfma_f32_16x16x32_bf16(a8, b0, c0, 0, 0, 0); \
        c1 = __builtin_amdgcn_mfma_f32_16x16x32_bf16(a8, b1, c1, 0, 0, 0); \
        c2 = __builtin_amdgcn_mfma_f32_16x16x32_bf16(a8, b2, c2, 0, 0, 0); \
        c3 = __builtin_amdgcn_mfma_f32_16x16x32_bf16(a8, b3, c3, 0, 0, 0); }
    KSTEP(0) KSTEP(1) KSTEP(2) KSTEP(3)
    #undef KSTEP

    // C/D layout: col = lane&15, row = (lane>>4)*4 + reg  [m89-verified]
    #pragma unroll
    for (int r = 0; r < 4; ++r) {
        int grow = rbase + koct * 4 + r;
        if (grow < n) {
            unsigned short* yp = y + (size_t)grow * OUT_CH + cl;
            yp[0]  = f2bf(c0[r]);
            yp[16] = f2bf(c1[r]);
            yp[32] = f2bf(c2[r]);
            yp[48] = f2bf(c3[r]);
        }
    }
}

// Gather (round-10 best): one wave per node, block=128 (32 waves/CU).
#define EDGE_FMA(c, v) \
    ax = fmaf(c, __uint_as_float((v) << 16), ax); \
    ay = fmaf(c, __uint_as_float((v) & 0xffff0000u), ay);

__global__ __launch_bounds__(128) void gather_kernel(const int* __restrict__ cnt,
                                                     const int* __restrict__ bucket,
                                                     const unsigned short* __restrict__ y,
                                                     const float* __restrict__ bias,
                                                     float* __restrict__ out, int n) {
    const int wid  = threadIdx.x >> 6;
    const int lane = threadIdx.x & 63;
    const int nid  = blockIdx.x * 2 + wid;
    if (nid >= n) return;
    const int hw = lane >> 5;
    const int cp = lane & 31;

    int deg = cnt[nid];
    if (deg > CAP) deg = CAP;
    const float isd_d = rsqrtf((float)cnt[nid] + 1.0f);

    int   s_l  = 0;
    float cf_l = 0.f;
    if (lane < deg) {
        s_l  = bucket[(size_t)nid * CAP + lane];
        cf_l = isd_d * rsqrtf((float)cnt[s_l] + 1.0f);
    }

    float ax = 0.f, ay = 0.f;
    if (hw == 0) {
        float2 b2 = reinterpret_cast<const float2*>(bias)[cp];
        unsigned int u = reinterpret_cast<const unsigned int*>(y + (size_t)nid * OUT_CH)[cp];
        float sl = isd_d * isd_d;
        ax = fmaf(sl, __uint_as_float(u << 16), b2.x);
        ay = fmaf(sl, __uint_as_float(u & 0xffff0000u), b2.y);
    }

    for (int k = 0; k < deg; k += 16) {
        int rem = deg - k;
        if (rem > 8) {
            int s0 = __shfl(s_l, k + 0 + hw),  s1 = __shfl(s_l, k + 2 + hw);
            int s2 = __shfl(s_l, k + 4 + hw),  s3 = __shfl(s_l, k + 6 + hw);
            int s4 = __shfl(s_l, k + 8 + hw),  s5 = __shfl(s_l, k + 10 + hw);
            int s6 = __shfl(s_l, k + 12 + hw), s7 = __shfl(s_l, k + 14 + hw);
            unsigned int v0 = reinterpret_cast<const unsigned int*>(y + (size_t)s0 * OUT_CH)[cp];
            unsigned int v1 = reinterpret_cast<const unsigned int*>(y + (size_t)s1 * OUT_CH)[cp];
            unsigned int v2 = reinterpret_cast<const unsigned int*>(y + (size_t)s2 * OUT_CH)[cp];
            unsigned int v3 = reinterpret_cast<const unsigned int*>(y + (size_t)s3 * OUT_CH)[cp];
            unsigned int v4 = reinterpret_cast<const unsigned int*>(y + (size_t)s4 * OUT_CH)[cp];
            unsigned int v5 = reinterpret_cast<const unsigned int*>(y + (size_t)s5 * OUT_CH)[cp];
            unsigned int v6 = reinterpret_cast<const unsigned int*>(y + (size_t)s6 * OUT_CH)[cp];
            unsigned int v7 = reinterpret_cast<const unsigned int*>(y + (size_t)s7 * OUT_CH)[cp];
            float c0 = __shfl(cf_l, k + 0 + hw),  c1 = __shfl(cf_l, k + 2 + hw);
            float c2 = __shfl(cf_l, k + 4 + hw),  c3 = __shfl(cf_l, k + 6 + hw);
            float c4 = __shfl(cf_l, k + 8 + hw),  c5 = __shfl(cf_l, k + 10 + hw);
            float c6 = __shfl(cf_l, k + 12 + hw), c7 = __shfl(cf_l, k + 14 + hw);
            EDGE_FMA(c0, v0) EDGE_FMA(c1, v1) EDGE_FMA(c2, v2) EDGE_FMA(c3, v3)
            EDGE_FMA(c4, v4) EDGE_FMA(c5, v5) EDGE_FMA(c6, v6) EDGE_FMA(c7, v7)
        } else {
            int s0 = __shfl(s_l, k + 0 + hw), s1 = __shfl(s_l, k + 2 + hw);
            int s2 = __shfl(s_l, k + 4 + hw), s3 = __shfl(s_l, k + 6 + hw);
            unsigned int v0 = reinterpret_cast<const unsigned int*>(y + (size_t)s0 * OUT_CH)[cp];
            unsigned int v1 = reinterpret_cast<const unsigned int*>(y + (size_t)s1 * OUT_CH)[cp];
            unsigned int v2 = reinterpret_cast<const unsigned int*>(y + (size_t)s2 * OUT_CH)[cp];
            unsigned int v3 = reinterpret_cast<const unsigned int*>(y + (size_t)s3 * OUT_CH)[cp];
            float c0 = __shfl(cf_l, k + 0 + hw), c1 = __shfl(cf_l, k + 2 + hw);
            float c2 = __shfl(cf_l, k + 4 + hw), c3 = __shfl(cf_l, k + 6 + hw);
            EDGE_FMA(c0, v0) EDGE_FMA(c1, v1) EDGE_FMA(c2, v2) EDGE_FMA(c3, v3)
        }
    }

    ax += __shfl_xor(ax, 32);
    ay += __shfl_xor(ay, 32);
    if (hw == 0) {
        float2 o; o.x = ax; o.y = ay;
        reinterpret_cast<float2*>(out + (size_t)nid * OUT_CH)[cp] = o;
    }
}

extern "C" void kernel_launch(void* const* d_in, const int* in_sizes, int n_in,
                              void* d_out, int out_size, void* d_ws, size_t ws_size,
                              hipStream_t stream) {
    const float* x    = (const float*)d_in[0];
    const int*   ei   = (const int*)d_in[1];
    const float* w    = (const float*)d_in[2];
    const float* bias = (const float*)d_in[3];
    float* out = (float*)d_out;

    const int n  = in_sizes[0] / IN_CH;   // 50000
    const int nE = in_sizes[1] / 2;       // 600000

    char* p = (char*)d_ws;
    auto align256 = [](size_t v) { return (v + 255) & ~(size_t)255; };
    int*            cnt    = (int*)p;             p += align256((size_t)n * 4);
    unsigned short* y      = (unsigned short*)p;  p += align256((size_t)n * OUT_CH * 2);
    int*            bucket = (int*)p;             p += align256((size_t)n * CAP * 4);
    unsigned short* wt     = (unsigned short*)p;  // 8192 ushort

    // 1) cnt = 0 and wt = bf16(W^T)
    zero_prep_kernel<<<(n + 255) / 256, 256, 0, stream>>>(cnt, w, wt, n);
    // 2) bucket blocks (1 pair/thread) || mfma-gemm blocks
    mega_kernel<<<TOTAL_BLOCKS, 256, 0, stream>>>(x, wt, ei, y, cnt, bucket, n, nE);
    // 3) gather
    gather_kernel<<<(n + 1) / 2, 128, 0, stream>>>(cnt, bucket, y, bias, out, n);
}